// Round 13
// baseline (95.537 us; speedup 1.0000x reference)
//
#include <hip/hip_runtime.h>

typedef __attribute__((ext_vector_type(8))) short bf16x8;
typedef __attribute__((ext_vector_type(4))) float f32x4;
typedef unsigned int uint32;
typedef unsigned short u16;

#define BN 1024
// K1 = 3 (reference: B, N, C, K1, CO = 8, 1024, 64, 3, 64)

// Module-scope stats scratch: sir, sii, sjr, sji, M, Z  (6 x 8192 f32 = 192 KB).
// Fully rewritten every kernel_launch call -> deterministic across graph replays.
__device__ __align__(16) float g_stats[6 * 8192];

__device__ __forceinline__ u16 f2bf(float x) {
    uint32 u = __float_as_uint(x);
    u += 0x7fffu + ((u >> 16) & 1u);
    return (u16)(u >> 16);
}
__device__ __forceinline__ float bf2f(u16 h) {
    return __uint_as_float(((uint32)h) << 16);
}

// ---------------- K0: si/sj projections: (B,N) x4.  Inputs f32. ----------------
__global__ void k_sisj(const float* __restrict__ Xr, const float* __restrict__ Xi,
                       const float* __restrict__ asr, const float* __restrict__ asi,
                       const float* __restrict__ adr, const float* __restrict__ adi) {
    int wid = threadIdx.x >> 6, lane = threadIdx.x & 63;
    int bn = blockIdx.x * 4 + wid;                 // 0..8191
    float xr = Xr[(size_t)bn * 64 + lane], xi = Xi[(size_t)bn * 64 + lane];
    float r0 = asr[lane], i0 = asi[lane], r1 = adr[lane], i1 = adi[lane];
    float v0 = xr * r0 - xi * i0;
    float v1 = xr * i0 + xi * r0;
    float v2 = xr * r1 - xi * i1;
    float v3 = xr * i1 + xi * r1;
    #pragma unroll
    for (int off = 32; off; off >>= 1) {
        v0 += __shfl_xor(v0, off);
        v1 += __shfl_xor(v1, off);
        v2 += __shfl_xor(v2, off);
        v3 += __shfl_xor(v3, off);
    }
    if (lane == 0) {
        g_stats[bn]         = v0;   // sir
        g_stats[8192 + bn]  = v1;   // sii
        g_stats[16384 + bn] = v2;   // sjr
        g_stats[24576 + bn] = v3;   // sji
    }
}

// ---------------- K1: per-(b,j) softmax stats over i ----------------
__global__ void k_mz(const float* __restrict__ pbr, const float* __restrict__ pbi,
                     const float* __restrict__ par, const float* __restrict__ pai) {
    int wid = threadIdx.x >> 6, lane = threadIdx.x & 63;
    int bj = blockIdx.x * 4 + wid;                 // 0..8191
    int b = bj >> 10;
    float br = pbr[0], bi = pbi[0], ar = par[0], ai = pai[0];
    float sjrv = g_stats[16384 + bj], sjiv = g_stats[24576 + bj];
    float mags[16];
    float mx = 0.0f;
    #pragma unroll
    for (int t = 0; t < 16; ++t) {
        int i = t * 64 + lane;
        float sr = g_stats[b * BN + i] + sjrv + br;
        float si = g_stats[8192 + b * BN + i] + sjiv + bi;
        sr = sr >= 0.f ? sr : ar * sr;
        si = si >= 0.f ? si : ai * si;
        float m = sqrtf(sr * sr + si * si);
        mags[t] = m;
        mx = fmaxf(mx, m);
    }
    #pragma unroll
    for (int off = 32; off; off >>= 1) mx = fmaxf(mx, __shfl_xor(mx, off));
    float s = 0.f;
    #pragma unroll
    for (int t = 0; t < 16; ++t) s += __expf(mags[t] - mx);
    #pragma unroll
    for (int off = 32; off; off >>= 1) s += __shfl_xor(s, off);
    if (lane == 0) { g_stats[32768 + bj] = mx; g_stats[40960 + bj] = s; }
}

// ---------------- K2: main fused kernel ----------------
// grid 512 = (b, i-block of 16). 4 waves; waves 0-2 own k=0..2 in stage 1,
// all 4 waves each own an o-quarter in stage 2.
__global__ __launch_bounds__(256) void k_main(
    const float* __restrict__ Lr, const float* __restrict__ Li,
    const float* __restrict__ Xr, const float* __restrict__ Xi,
    const float* __restrict__ wr, const float* __restrict__ wi,
    const float* __restrict__ pbr, const float* __restrict__ pbi,
    const float* __restrict__ par, const float* __restrict__ pai,
    float* __restrict__ out) {
    // lmS: [k3][rc2][16][72] (6912) ; xS: [rc2][64][72] @6912 (9216)  -> 16128 u16
    // epilogue reuse: LXs [plane4][16][200] (12800)
    __shared__ __align__(16) u16 smem[16128];
    __shared__ __align__(16) float sA[2][16];
    u16* lmS = smem;
    u16* xS  = smem + 6912;

    int tid = threadIdx.x, wid = tid >> 6, lane = tid & 63;
    int b = blockIdx.x >> 6, it = blockIdx.x & 63, i0 = it * 16;

    const float* sir_g = g_stats;
    const float* sii_g = g_stats + 8192;
    const float* sjr_g = g_stats + 16384;
    const float* sji_g = g_stats + 24576;
    const float* Mv_g  = g_stats + 32768;
    const float* Zv_g  = g_stats + 40960;

    if (tid < 32) {
        int p = tid >> 4, i = tid & 15;
        sA[p][i] = (p ? sii_g : sir_g)[b * BN + i0 + i];
    }

    f32x4 zz = {0.f, 0.f, 0.f, 0.f};
    f32x4 accr[4], acci[4];
    #pragma unroll
    for (int nt = 0; nt < 4; ++nt) { accr[nt] = zz; acci[nt] = zz; }

    float br = pbr[0], bi = pbi[0], alr = par[0], ali = pai[0];

    int task = tid >> 1, khalf = tid & 1;
    int ti = task >> 3, tj8 = task & 7;            // row 0..15, j-run 0..7

    __syncthreads();
    float sirv = sA[0][ti], siiv = sA[1][ti];

    for (int q = 0; q < 16; ++q) {
        int j0 = q * 64;
        // ---- X^T staging: strided-but-lane-coalesced global f32 reads -> bf16 LDS ----
        #pragma unroll
        for (int s = 0; s < 4; ++s) {
            int t2 = s * 256 + tid;
            int c = t2 & 63, rest = t2 >> 6;
            int j8 = rest & 7, p = rest >> 3;
            const float* src = p ? Xi : Xr;
            size_t base = ((size_t)b * BN + j0 + j8 * 8) * 64 + c;
            union { u16 h[8]; uint4 v; } pk;
            #pragma unroll
            for (int jj = 0; jj < 8; ++jj) pk.h[jj] = f2bf(src[base + (size_t)jj * 64]);
            *(uint4*)(xS + (p * 64 + c) * 72 + j8 * 8) = pk.v;
        }
        // ---- attention a_ij for (ti, 8 j's) ----
        int jj0 = j0 + tj8 * 8;
        float4 A0 = *(const float4*)&sjr_g[b * BN + jj0], A1 = *(const float4*)&sjr_g[b * BN + jj0 + 4];
        float4 B0 = *(const float4*)&sji_g[b * BN + jj0], B1 = *(const float4*)&sji_g[b * BN + jj0 + 4];
        float4 C0 = *(const float4*)&Mv_g[b * BN + jj0],  C1 = *(const float4*)&Mv_g[b * BN + jj0 + 4];
        float4 D0 = *(const float4*)&Zv_g[b * BN + jj0],  D1 = *(const float4*)&Zv_g[b * BN + jj0 + 4];
        float sjr8[8] = {A0.x, A0.y, A0.z, A0.w, A1.x, A1.y, A1.z, A1.w};
        float sji8[8] = {B0.x, B0.y, B0.z, B0.w, B1.x, B1.y, B1.z, B1.w};
        float M8[8]   = {C0.x, C0.y, C0.z, C0.w, C1.x, C1.y, C1.z, C1.w};
        float Z8[8]   = {D0.x, D0.y, D0.z, D0.w, D1.x, D1.y, D1.z, D1.w};
        float arj[8], aij[8];
        #pragma unroll
        for (int e = 0; e < 8; ++e) {
            float sr = sirv + sjr8[e] + br;
            float si = siiv + sji8[e] + bi;
            sr = sr >= 0.f ? sr : alr * sr;
            si = si >= 0.f ? si : ali * si;
            float mg = sqrtf(sr * sr + si * si);
            float sc = __expf(mg - M8[e]) / (Z8[e] * fmaxf(mg, 1e-12f));
            arj[e] = sc * sr;
            aij[e] = sc * si;
        }
        // ---- Lm modulate + stage (bf16): khalf=0 stages k=0,1; khalf=1 stages k=2 ----
        auto stageK = [&](int k) {
            size_t lbase = ((size_t)(b * 3 + k) * BN + (i0 + ti)) * BN + jj0;
            const float* lp = Lr + lbase;
            const float* lq = Li + lbase;
            float4 r0 = ((const float4*)lp)[0], r1 = ((const float4*)lp)[1];
            float4 s0 = ((const float4*)lq)[0], s1 = ((const float4*)lq)[1];
            float lr8[8] = {r0.x, r0.y, r0.z, r0.w, r1.x, r1.y, r1.z, r1.w};
            float li8[8] = {s0.x, s0.y, s0.z, s0.w, s1.x, s1.y, s1.z, s1.w};
            union { u16 h[8]; uint4 v; } pr, pi;
            #pragma unroll
            for (int e = 0; e < 8; ++e) {
                float mr = lr8[e] * arj[e] - li8[e] * aij[e];
                float mi = lr8[e] * aij[e] + li8[e] * arj[e];
                pr.h[e] = f2bf(mr);
                pi.h[e] = f2bf(mi);
            }
            *(uint4*)(lmS + ((k * 2 + 0) * 16 + ti) * 72 + tj8 * 8) = pr.v;
            *(uint4*)(lmS + ((k * 2 + 1) * 16 + ti) * 72 + tj8 * 8) = pi.v;
        };
        if (khalf == 0) { stageK(0); stageK(1); } else { stageK(2); }
        __syncthreads();
        // ---- MFMA: waves 0-2 own k=wid; wave 3 idles ----
        if (wid < 3) {
            int arow = lane & 15, kb = (lane >> 4) * 8;
            #pragma unroll
            for (int ks = 0; ks < 2; ++ks) {
                int kc = ks * 32 + kb;
                bf16x8 aR = *(const bf16x8*)(lmS + ((wid * 2 + 0) * 16 + arow) * 72 + kc);
                bf16x8 aI = *(const bf16x8*)(lmS + ((wid * 2 + 1) * 16 + arow) * 72 + kc);
                bf16x8 aIn;
                #pragma unroll
                for (int z = 0; z < 8; ++z) aIn[z] = (short)(aI[z] ^ (short)0x8000);
                #pragma unroll
                for (int nt = 0; nt < 4; ++nt) {
                    int crow = nt * 16 + arow;
                    bf16x8 xr = *(const bf16x8*)(xS + (0 * 64 + crow) * 72 + kc);
                    bf16x8 xi = *(const bf16x8*)(xS + (1 * 64 + crow) * 72 + kc);
                    accr[nt] = __builtin_amdgcn_mfma_f32_16x16x32_bf16(aR,  xr, accr[nt], 0, 0, 0);
                    accr[nt] = __builtin_amdgcn_mfma_f32_16x16x32_bf16(aIn, xi, accr[nt], 0, 0, 0);
                    acci[nt] = __builtin_amdgcn_mfma_f32_16x16x32_bf16(aR,  xi, acci[nt], 0, 0, 0);
                    acci[nt] = __builtin_amdgcn_mfma_f32_16x16x32_bf16(aI,  xr, acci[nt], 0, 0, 0);
                }
            }
        }
        __syncthreads();
    }

    // ---- epilogue: LX -> LDS bf16 hi/lo; planes: 0=r-hi,1=r-lo,2=i-hi,3=i-lo ----
    u16* LXs = smem;  // [4][16][200], kc in [0,192)
    if (wid < 3) {
        #pragma unroll
        for (int p = 0; p < 2; ++p) {
            #pragma unroll
            for (int nt = 0; nt < 4; ++nt) {
                f32x4 fr = p ? acci[nt] : accr[nt];
                #pragma unroll
                for (int r = 0; r < 4; ++r) {
                    int i = (lane >> 4) * 4 + r;
                    int kc = wid * 64 + nt * 16 + (lane & 15);
                    float v = fr[r];
                    u16 hi = f2bf(v);
                    u16 lo = f2bf(v - bf2f(hi));
                    LXs[((p * 2 + 0) * 16 + i) * 200 + kc] = hi;
                    LXs[((p * 2 + 1) * 16 + i) * 200 + kc] = lo;
                }
            }
        }
    }
    __syncthreads();
    // ---- stage 2: out[i][o] = LX @ w (complex; LX hi/lo in LDS, w f32 hi/lo) ----
    {
        f32x4 o_r = zz, o_i = zz;
        int arow = lane & 15, kb = (lane >> 4) * 8;
        int o = wid * 16 + arow;
        #pragma unroll
        for (int ks = 0; ks < 6; ++ks) {
            int kc = ks * 32 + kb;
            bf16x8 Arh = *(const bf16x8*)(LXs + (0 * 16 + arow) * 200 + kc);
            bf16x8 Arl = *(const bf16x8*)(LXs + (1 * 16 + arow) * 200 + kc);
            bf16x8 Aih = *(const bf16x8*)(LXs + (2 * 16 + arow) * 200 + kc);
            bf16x8 Ail = *(const bf16x8*)(LXs + (3 * 16 + arow) * 200 + kc);
            union { u16 h[8]; bf16x8 v; } Wrh, Wrl, Wih, Wil, Wihn, Wiln;
            #pragma unroll
            for (int jj = 0; jj < 8; ++jj) {
                float vr = wr[(size_t)(kc + jj) * 64 + o];
                float vi = wi[(size_t)(kc + jj) * 64 + o];
                u16 rh = f2bf(vr);
                u16 rl = f2bf(vr - bf2f(rh));
                u16 ih = f2bf(vi);
                u16 il = f2bf(vi - bf2f(ih));
                Wrh.h[jj] = rh; Wrl.h[jj] = rl;
                Wih.h[jj] = ih; Wil.h[jj] = il;
                Wihn.h[jj] = (u16)(ih ^ 0x8000u);
                Wiln.h[jj] = (u16)(il ^ 0x8000u);
            }
            o_r = __builtin_amdgcn_mfma_f32_16x16x32_bf16(Arh, Wrh.v,  o_r, 0, 0, 0);
            o_r = __builtin_amdgcn_mfma_f32_16x16x32_bf16(Arh, Wrl.v,  o_r, 0, 0, 0);
            o_r = __builtin_amdgcn_mfma_f32_16x16x32_bf16(Arl, Wrh.v,  o_r, 0, 0, 0);
            o_r = __builtin_amdgcn_mfma_f32_16x16x32_bf16(Aih, Wihn.v, o_r, 0, 0, 0);
            o_r = __builtin_amdgcn_mfma_f32_16x16x32_bf16(Aih, Wiln.v, o_r, 0, 0, 0);
            o_r = __builtin_amdgcn_mfma_f32_16x16x32_bf16(Ail, Wihn.v, o_r, 0, 0, 0);
            o_i = __builtin_amdgcn_mfma_f32_16x16x32_bf16(Arh, Wih.v,  o_i, 0, 0, 0);
            o_i = __builtin_amdgcn_mfma_f32_16x16x32_bf16(Arh, Wil.v,  o_i, 0, 0, 0);
            o_i = __builtin_amdgcn_mfma_f32_16x16x32_bf16(Arl, Wih.v,  o_i, 0, 0, 0);
            o_i = __builtin_amdgcn_mfma_f32_16x16x32_bf16(Aih, Wrh.v,  o_i, 0, 0, 0);
            o_i = __builtin_amdgcn_mfma_f32_16x16x32_bf16(Aih, Wrl.v,  o_i, 0, 0, 0);
            o_i = __builtin_amdgcn_mfma_f32_16x16x32_bf16(Ail, Wrh.v,  o_i, 0, 0, 0);
        }
        #pragma unroll
        for (int r = 0; r < 4; ++r) {
            int i = (lane >> 4) * 4 + r;
            size_t off = ((size_t)b * BN + i0 + i) * 64 + o;
            out[off] = o_r[r];
            out[524288 + off] = o_i[r];
        }
    }
}

extern "C" void kernel_launch(void* const* d_in, const int* in_sizes, int n_in,
                              void* d_out, int out_size, void* d_ws, size_t ws_size,
                              hipStream_t stream) {
    const float* Xr  = (const float*)d_in[0];
    const float* Xi  = (const float*)d_in[1];
    const float* Lr  = (const float*)d_in[2];
    const float* Li  = (const float*)d_in[3];
    const float* asr = (const float*)d_in[4];
    const float* asi = (const float*)d_in[5];
    const float* adr = (const float*)d_in[6];
    const float* adi = (const float*)d_in[7];
    const float* pbr = (const float*)d_in[8];
    const float* pbi = (const float*)d_in[9];
    const float* par = (const float*)d_in[10];
    const float* pai = (const float*)d_in[11];
    const float* wr  = (const float*)d_in[12];
    const float* wi  = (const float*)d_in[13];
    float* out = (float*)d_out;

    k_sisj<<<2048, 256, 0, stream>>>(Xr, Xi, asr, asi, adr, adi);
    k_mz<<<2048, 256, 0, stream>>>(pbr, pbi, par, pai);
    k_main<<<512, 256, 0, stream>>>(Lr, Li, Xr, Xi, wr, wi,
                                    pbr, pbi, par, pai, out);
}

// Round 15
// 75.434 us; speedup vs baseline: 1.2665x; 1.2665x over previous
//
#include <hip/hip_runtime.h>

typedef __attribute__((ext_vector_type(8))) short bf16x8;
typedef __attribute__((ext_vector_type(4))) float f32x4;
typedef unsigned int uint32;
typedef unsigned short u16;

#define BN 1024
// K1 = 3; inputs f32, output f32.

// Device-global scratch (module-load allocated; fully rewritten every call).
__device__ __align__(16) float g_stats[6 * 8192];          // sir,sii,sjr,sji,M,Z
__device__ __align__(16) u16   g_Xt[8 * 16 * 2 * 64 * 64]; // X^T bf16 [b][q][p][c][j]
__device__ __align__(16) u16   g_wt[6 * 64 * 192];         // w bf16 [plane][o][kc]; planes: rh,rl,ih,il,-ih,-il
__device__ __align__(16) float g_part[1024 * 6144];        // partial LX [blk][rc2][16][192]

__device__ __forceinline__ u16 f2bf(float x) {
    uint32 u = __float_as_uint(x);
    u += 0x7fffu + ((u >> 16) & 1u);
    return (u16)(u >> 16);
}
__device__ __forceinline__ float bf2f(u16 h) {
    return __uint_as_float(((uint32)h) << 16);
}

// ---------------- K0: si/sj projections ----------------
__global__ void k_sisj(const float* __restrict__ Xr, const float* __restrict__ Xi,
                       const float* __restrict__ asr, const float* __restrict__ asi,
                       const float* __restrict__ adr, const float* __restrict__ adi) {
    int wid = threadIdx.x >> 6, lane = threadIdx.x & 63;
    int bn = blockIdx.x * 4 + wid;
    float xr = Xr[(size_t)bn * 64 + lane], xi = Xi[(size_t)bn * 64 + lane];
    float r0 = asr[lane], i0 = asi[lane], r1 = adr[lane], i1 = adi[lane];
    float v0 = xr * r0 - xi * i0;
    float v1 = xr * i0 + xi * r0;
    float v2 = xr * r1 - xi * i1;
    float v3 = xr * i1 + xi * r1;
    #pragma unroll
    for (int off = 32; off; off >>= 1) {
        v0 += __shfl_xor(v0, off);
        v1 += __shfl_xor(v1, off);
        v2 += __shfl_xor(v2, off);
        v3 += __shfl_xor(v3, off);
    }
    if (lane == 0) {
        g_stats[bn]         = v0;
        g_stats[8192 + bn]  = v1;
        g_stats[16384 + bn] = v2;
        g_stats[24576 + bn] = v3;
    }
}

// ---------------- K1: per-(b,j) softmax stats over i ----------------
__global__ void k_mz(const float* __restrict__ pbr, const float* __restrict__ pbi,
                     const float* __restrict__ par, const float* __restrict__ pai) {
    int wid = threadIdx.x >> 6, lane = threadIdx.x & 63;
    int bj = blockIdx.x * 4 + wid;
    int b = bj >> 10;
    float br = pbr[0], bi = pbi[0], ar = par[0], ai = pai[0];
    float sjrv = g_stats[16384 + bj], sjiv = g_stats[24576 + bj];
    float mags[16];
    float mx = 0.0f;
    #pragma unroll
    for (int t = 0; t < 16; ++t) {
        int i = t * 64 + lane;
        float sr = g_stats[b * BN + i] + sjrv + br;
        float si = g_stats[8192 + b * BN + i] + sjiv + bi;
        sr = sr >= 0.f ? sr : ar * sr;
        si = si >= 0.f ? si : ai * si;
        float m = sqrtf(sr * sr + si * si);
        mags[t] = m;
        mx = fmaxf(mx, m);
    }
    #pragma unroll
    for (int off = 32; off; off >>= 1) mx = fmaxf(mx, __shfl_xor(mx, off));
    float s = 0.f;
    #pragma unroll
    for (int t = 0; t < 16; ++t) s += __expf(mags[t] - mx);
    #pragma unroll
    for (int off = 32; off; off >>= 1) s += __shfl_xor(s, off);
    if (lane == 0) { g_stats[32768 + bj] = mx; g_stats[40960 + bj] = s; }
}

// ---------------- K2a: X -> transposed bf16 g_Xt[b][q][p][c][j] ----------------
__global__ void k_xt(const float* __restrict__ Xr, const float* __restrict__ Xi) {
    int b = blockIdx.x >> 4, q = blockIdx.x & 15;
    __shared__ float xs[2][64][65];
    int tid = threadIdx.x;
    #pragma unroll 4
    for (int rep = 0; rep < 32; ++rep) {
        int idx = rep * 256 + tid;                  // 8192
        int p = idx >> 12, j = (idx >> 6) & 63, c = idx & 63;
        const float* src = p ? Xi : Xr;
        xs[p][j][c] = src[((size_t)b * BN + q * 64 + j) * 64 + c];
    }
    __syncthreads();
    #pragma unroll
    for (int rep = 0; rep < 4; ++rep) {
        int idx = rep * 256 + tid;                  // 1024 uint4
        int p = idx >> 9, c = (idx >> 3) & 63, j8 = idx & 7;
        union { u16 h[8]; uint4 v; } pk;
        #pragma unroll
        for (int jj = 0; jj < 8; ++jj) pk.h[jj] = f2bf(xs[p][j8 * 8 + jj][c]);
        *(uint4*)&g_Xt[(size_t)(((b * 16 + q) * 2 + p) * 64 + c) * 64 + j8 * 8] = pk.v;
    }
}

// ---------------- K2b: w -> bf16 hi/lo planes g_wt[plane][o][kc] ----------------
__global__ void k_wt(const float* __restrict__ wr, const float* __restrict__ wi) {
    int t = blockIdx.x * 256 + threadIdx.x;         // 0..12287 ; w[k][c][o], t = kc*64+o
    int o = t & 63, kc = t >> 6;
    float vr = wr[t], vi = wi[t];
    u16 rh = f2bf(vr);
    u16 rl = f2bf(vr - bf2f(rh));
    u16 ih = f2bf(vi);
    u16 il = f2bf(vi - bf2f(ih));
    g_wt[(0 * 64 + o) * 192 + kc] = rh;
    g_wt[(1 * 64 + o) * 192 + kc] = rl;
    g_wt[(2 * 64 + o) * 192 + kc] = ih;
    g_wt[(3 * 64 + o) * 192 + kc] = il;
    g_wt[(4 * 64 + o) * 192 + kc] = (u16)(ih ^ 0x8000u);
    g_wt[(5 * 64 + o) * 192 + kc] = (u16)(il ^ 0x8000u);
}

// ---------------- K3: main kernel: partial LX over half the j range ----------------
// grid 1024 = b(8) x it(64) x jh(2); 256 threads; thread owns (ti row, 4 j's, all 3 k).
__global__ __launch_bounds__(256) void k_main(
    const float* __restrict__ Lr, const float* __restrict__ Li,
    const float* __restrict__ pbr, const float* __restrict__ pbi,
    const float* __restrict__ par, const float* __restrict__ pai) {
    // lmS: [k3][rc2][16][72] (6912) ; xS: [rc2][64][72] @6912 (9216) -> 16128 u16
    __shared__ __align__(16) u16 smem[16128];
    __shared__ __align__(16) float sA[2][16];
    u16* lmS = smem;
    u16* xS  = smem + 6912;

    int tid = threadIdx.x, wid = tid >> 6, lane = tid & 63;
    int jh = blockIdx.x & 1, it = (blockIdx.x >> 1) & 63, b = blockIdx.x >> 7;
    int i0 = it * 16;

    const float* sjr_g = g_stats + 16384;
    const float* sji_g = g_stats + 24576;
    const float* Mv_g  = g_stats + 32768;
    const float* Zv_g  = g_stats + 40960;

    if (tid < 32) {
        int p = tid >> 4, i = tid & 15;
        sA[p][i] = g_stats[p * 8192 + b * BN + i0 + i];
    }

    f32x4 zz = {0.f, 0.f, 0.f, 0.f};
    f32x4 accr[4], acci[4];
    #pragma unroll
    for (int nt = 0; nt < 4; ++nt) { accr[nt] = zz; acci[nt] = zz; }

    float brv = pbr[0], biv = pbi[0], alrv = par[0], aliv = pai[0];

    int ti = tid >> 4, tj4 = tid & 15;              // row 0..15, j-run of 4

    __syncthreads();
    float sirv = sA[0][ti], siiv = sA[1][ti];

    for (int qi = 0; qi < 8; ++qi) {
        int q = jh * 8 + qi;
        int j0 = q * 64;
        // ---- X^T staging: 4 uint4 LDS copies from precomputed g_Xt ----
        #pragma unroll
        for (int s = 0; s < 4; ++s) {
            int idx = s * 256 + tid;
            int p = idx >> 9, c = (idx >> 3) & 63, j8 = idx & 7;
            uint4 v = *(const uint4*)&g_Xt[(size_t)(((b * 16 + q) * 2 + p) * 64 + c) * 64 + j8 * 8];
            *(uint4*)(xS + (p * 64 + c) * 72 + j8 * 8) = v;
        }
        // ---- attention for this thread's 4 j's (computed ONCE, reused for 3 k's) ----
        int jj0 = j0 + tj4 * 4;
        float4 A = *(const float4*)&sjr_g[b * BN + jj0];
        float4 Bv = *(const float4*)&sji_g[b * BN + jj0];
        float4 C = *(const float4*)&Mv_g[b * BN + jj0];
        float4 D = *(const float4*)&Zv_g[b * BN + jj0];
        float sjr4[4] = {A.x, A.y, A.z, A.w};
        float sji4[4] = {Bv.x, Bv.y, Bv.z, Bv.w};
        float M4[4]   = {C.x, C.y, C.z, C.w};
        float Z4[4]   = {D.x, D.y, D.z, D.w};
        float arj[4], aij[4];
        #pragma unroll
        for (int e = 0; e < 4; ++e) {
            float sr = sirv + sjr4[e] + brv;
            float si = siiv + sji4[e] + biv;
            sr = sr >= 0.f ? sr : alrv * sr;
            si = si >= 0.f ? si : aliv * si;
            float mg = sqrtf(sr * sr + si * si);
            float sc = __expf(mg - M4[e]) / (Z4[e] * fmaxf(mg, 1e-12f));
            arj[e] = sc * sr;
            aij[e] = sc * si;
        }
        // ---- Lm modulate + stage (bf16) for all 3 k's ----
        #pragma unroll
        for (int k = 0; k < 3; ++k) {
            size_t lbase = ((size_t)(b * 3 + k) * BN + (i0 + ti)) * BN + jj0;
            float4 r4 = *(const float4*)&Lr[lbase];
            float4 s4 = *(const float4*)&Li[lbase];
            float lr4[4] = {r4.x, r4.y, r4.z, r4.w};
            float li4[4] = {s4.x, s4.y, s4.z, s4.w};
            union { u16 h[4]; uint2 v; } pr, pi;
            #pragma unroll
            for (int e = 0; e < 4; ++e) {
                float mr = lr4[e] * arj[e] - li4[e] * aij[e];
                float mi = lr4[e] * aij[e] + li4[e] * arj[e];
                pr.h[e] = f2bf(mr);
                pi.h[e] = f2bf(mi);
            }
            *(uint2*)(lmS + ((k * 2 + 0) * 16 + ti) * 72 + tj4 * 4) = pr.v;
            *(uint2*)(lmS + ((k * 2 + 1) * 16 + ti) * 72 + tj4 * 4) = pi.v;
        }
        __syncthreads();
        // ---- MFMA: waves 0-2 own k=wid ----
        if (wid < 3) {
            int arow = lane & 15, kb = (lane >> 4) * 8;
            #pragma unroll
            for (int ks = 0; ks < 2; ++ks) {
                int kc = ks * 32 + kb;
                bf16x8 aR = *(const bf16x8*)(lmS + ((wid * 2 + 0) * 16 + arow) * 72 + kc);
                bf16x8 aI = *(const bf16x8*)(lmS + ((wid * 2 + 1) * 16 + arow) * 72 + kc);
                bf16x8 aIn;
                #pragma unroll
                for (int z = 0; z < 8; ++z) aIn[z] = (short)(aI[z] ^ (short)0x8000);
                #pragma unroll
                for (int nt = 0; nt < 4; ++nt) {
                    int crow = nt * 16 + arow;
                    bf16x8 xr = *(const bf16x8*)(xS + (0 * 64 + crow) * 72 + kc);
                    bf16x8 xi = *(const bf16x8*)(xS + (1 * 64 + crow) * 72 + kc);
                    accr[nt] = __builtin_amdgcn_mfma_f32_16x16x32_bf16(aR,  xr, accr[nt], 0, 0, 0);
                    accr[nt] = __builtin_amdgcn_mfma_f32_16x16x32_bf16(aIn, xi, accr[nt], 0, 0, 0);
                    acci[nt] = __builtin_amdgcn_mfma_f32_16x16x32_bf16(aR,  xi, acci[nt], 0, 0, 0);
                    acci[nt] = __builtin_amdgcn_mfma_f32_16x16x32_bf16(aI,  xr, acci[nt], 0, 0, 0);
                }
            }
        }
        __syncthreads();
    }

    // ---- write partial LX (f32) ----
    if (wid < 3) {
        size_t base = (size_t)blockIdx.x * 6144;
        #pragma unroll
        for (int p = 0; p < 2; ++p) {
            #pragma unroll
            for (int nt = 0; nt < 4; ++nt) {
                f32x4 fr = p ? acci[nt] : accr[nt];
                #pragma unroll
                for (int r = 0; r < 4; ++r) {
                    int row = (lane >> 4) * 4 + r;
                    int kc = wid * 64 + nt * 16 + (lane & 15);
                    g_part[base + (size_t)(p * 16 + row) * 192 + kc] = fr[r];
                }
            }
        }
    }
}

// ---------------- K4: combine partials + stage 2 -> out ----------------
__global__ __launch_bounds__(256) void k_out(float* __restrict__ out) {
    __shared__ __align__(16) u16 LXs[12800];   // [plane4][16][200], kc in [0,192)
    int tid = threadIdx.x, wid = tid >> 6, lane = tid & 63;
    int b = blockIdx.x >> 6, it = blockIdx.x & 63, i0 = it * 16;
    size_t p0 = (size_t)((b * 64 + it) * 2 + 0) * 6144;
    size_t p1 = p0 + 6144;

    #pragma unroll
    for (int rep = 0; rep < 6; ++rep) {
        int idx = rep * 256 + tid;                // 1536 float4
        float4 a = *(const float4*)&g_part[p0 + (size_t)idx * 4];
        float4 c = *(const float4*)&g_part[p1 + (size_t)idx * 4];
        float s[4] = {a.x + c.x, a.y + c.y, a.z + c.z, a.w + c.w};
        int f0 = idx * 4;
        int rc = f0 / 3072, rem = f0 - rc * 3072;
        int row = rem / 192, kc = rem - row * 192;
        #pragma unroll
        for (int t = 0; t < 4; ++t) {
            float v = s[t];
            u16 hi = f2bf(v);
            u16 lo = f2bf(v - bf2f(hi));
            LXs[((rc * 2 + 0) * 16 + row) * 200 + kc + t] = hi;
            LXs[((rc * 2 + 1) * 16 + row) * 200 + kc + t] = lo;
        }
    }
    __syncthreads();

    f32x4 zz = {0.f, 0.f, 0.f, 0.f};
    f32x4 o_r = zz, o_i = zz;
    int arow = lane & 15, kb = (lane >> 4) * 8;
    int o = wid * 16 + arow;
    #pragma unroll
    for (int ks = 0; ks < 6; ++ks) {
        int kc = ks * 32 + kb;
        bf16x8 Arh = *(const bf16x8*)(LXs + (0 * 16 + arow) * 200 + kc);
        bf16x8 Arl = *(const bf16x8*)(LXs + (1 * 16 + arow) * 200 + kc);
        bf16x8 Aih = *(const bf16x8*)(LXs + (2 * 16 + arow) * 200 + kc);
        bf16x8 Ail = *(const bf16x8*)(LXs + (3 * 16 + arow) * 200 + kc);
        bf16x8 Wrh  = *(const bf16x8*)&g_wt[(0 * 64 + o) * 192 + kc];
        bf16x8 Wrl  = *(const bf16x8*)&g_wt[(1 * 64 + o) * 192 + kc];
        bf16x8 Wih  = *(const bf16x8*)&g_wt[(2 * 64 + o) * 192 + kc];
        bf16x8 Wil  = *(const bf16x8*)&g_wt[(3 * 64 + o) * 192 + kc];
        bf16x8 Wihn = *(const bf16x8*)&g_wt[(4 * 64 + o) * 192 + kc];
        bf16x8 Wiln = *(const bf16x8*)&g_wt[(5 * 64 + o) * 192 + kc];
        o_r = __builtin_amdgcn_mfma_f32_16x16x32_bf16(Arh, Wrh,  o_r, 0, 0, 0);
        o_r = __builtin_amdgcn_mfma_f32_16x16x32_bf16(Arh, Wrl,  o_r, 0, 0, 0);
        o_r = __builtin_amdgcn_mfma_f32_16x16x32_bf16(Arl, Wrh,  o_r, 0, 0, 0);
        o_r = __builtin_amdgcn_mfma_f32_16x16x32_bf16(Aih, Wihn, o_r, 0, 0, 0);
        o_r = __builtin_amdgcn_mfma_f32_16x16x32_bf16(Aih, Wiln, o_r, 0, 0, 0);
        o_r = __builtin_amdgcn_mfma_f32_16x16x32_bf16(Ail, Wihn, o_r, 0, 0, 0);
        o_i = __builtin_amdgcn_mfma_f32_16x16x32_bf16(Arh, Wih,  o_i, 0, 0, 0);
        o_i = __builtin_amdgcn_mfma_f32_16x16x32_bf16(Arh, Wil,  o_i, 0, 0, 0);
        o_i = __builtin_amdgcn_mfma_f32_16x16x32_bf16(Arl, Wih,  o_i, 0, 0, 0);
        o_i = __builtin_amdgcn_mfma_f32_16x16x32_bf16(Aih, Wrh,  o_i, 0, 0, 0);
        o_i = __builtin_amdgcn_mfma_f32_16x16x32_bf16(Aih, Wrl,  o_i, 0, 0, 0);
        o_i = __builtin_amdgcn_mfma_f32_16x16x32_bf16(Ail, Wrh,  o_i, 0, 0, 0);
    }
    #pragma unroll
    for (int r = 0; r < 4; ++r) {
        int i = (lane >> 4) * 4 + r;
        size_t off = ((size_t)b * BN + i0 + i) * 64 + o;
        out[off] = o_r[r];
        out[524288 + off] = o_i[r];
    }
}

extern "C" void kernel_launch(void* const* d_in, const int* in_sizes, int n_in,
                              void* d_out, int out_size, void* d_ws, size_t ws_size,
                              hipStream_t stream) {
    const float* Xr  = (const float*)d_in[0];
    const float* Xi  = (const float*)d_in[1];
    const float* Lr  = (const float*)d_in[2];
    const float* Li  = (const float*)d_in[3];
    const float* asr = (const float*)d_in[4];
    const float* asi = (const float*)d_in[5];
    const float* adr = (const float*)d_in[6];
    const float* adi = (const float*)d_in[7];
    const float* pbr = (const float*)d_in[8];
    const float* pbi = (const float*)d_in[9];
    const float* par = (const float*)d_in[10];
    const float* pai = (const float*)d_in[11];
    const float* wr  = (const float*)d_in[12];
    const float* wi  = (const float*)d_in[13];
    float* out = (float*)d_out;

    k_sisj<<<2048, 256, 0, stream>>>(Xr, Xi, asr, asi, adr, adi);
    k_mz<<<2048, 256, 0, stream>>>(pbr, pbi, par, pai);
    k_xt<<<128, 256, 0, stream>>>(Xr, Xi);
    k_wt<<<48, 256, 0, stream>>>(wr, wi);
    k_main<<<1024, 256, 0, stream>>>(Lr, Li, pbr, pbi, par, pai);
    k_out<<<512, 256, 0, stream>>>(out);
}